// Round 5
// baseline (410.023 us; speedup 1.0000x reference)
//
#include <hip/hip_runtime.h>

#define BB 64
#define JJ 24
#define TT 2048
#define NELEM (BB*JJ*6*TT)              // 18,874,368 floats
#define NVEL  ((long long)BB*JJ*6*(TT-1))
#define FOOT_BLOCKS 256
#define RBLOCKS 4608                    // 4608*256 threads * 16 floats = NELEM
#define NBLK (FOOT_BLOCKS + RBLOCKS)    // 4864

__device__ __forceinline__ void block_reduce2f(float& a, float& b) {
    #pragma unroll
    for (int off = 32; off > 0; off >>= 1) {
        a += __shfl_down(a, off);
        b += __shfl_down(b, off);
    }
    __shared__ float sa[4], sb[4];
    const int lane = threadIdx.x & 63;
    const int wid  = threadIdx.x >> 6;
    if (lane == 0) { sa[wid] = a; sb[wid] = b; }
    __syncthreads();
    if (threadIdx.x == 0) {
        for (int w = 1; w < 4; ++w) { a += sa[w]; b += sb[w]; }
    }
}

__device__ __forceinline__ float sigm(float y) {
    return 1.f / (1.f + __expf(-(0.05f - y) * 20.f));
}

// d_ws layout: [0..3] counter (memset to 0), [256..] double2 parts[NBLK]
__global__ __launch_bounds__(256) void fused_kernel(
        const float* __restrict__ pred, const float* __restrict__ targ,
        const float* __restrict__ jp, unsigned* __restrict__ counter,
        double2* __restrict__ parts, float* __restrict__ out) {

    if (blockIdx.x < FOOT_BLOCKS) {
        // ---------------- foot-contact loss: one block per (b, foot) ----------
        const int FI[4] = {7, 8, 10, 11};
        const int bf = blockIdx.x;
        const int b  = bf >> 2;
        const int j  = FI[bf & 3];
        const float* __restrict__ xrow = jp + ((size_t)(b * JJ + j) * 3) * TT;
        const float* __restrict__ yrow = xrow + TT;
        const float* __restrict__ zrow = xrow + 2 * TT;
        const float4* __restrict__ x4 = reinterpret_cast<const float4*>(xrow);
        const float4* __restrict__ y4 = reinterpret_cast<const float4*>(yrow);
        const float4* __restrict__ z4 = reinterpret_cast<const float4*>(zrow);

        float lsum = 0.f, csum = 0.f;
        #pragma unroll
        for (int cc = 0; cc < 2; ++cc) {
            const int c = threadIdx.x + cc * 256;         // chunk: t in [4c, 4c+4)
            const float4 xv = x4[c], yv = y4[c], zv = z4[c];
            float x0 = 0.f, y0 = 0.f, z0 = 0.f;
            if (c > 0) { x0 = xrow[4*c-1]; y0 = yrow[4*c-1]; z0 = zrow[4*c-1]; }
            const float w0 = sigm(y0),  w1 = sigm(yv.x), w2 = sigm(yv.y),
                        w3 = sigm(yv.z), w4 = sigm(yv.w);
            auto term = [&](float x1, float xp, float z1, float zp,
                            float wa, float wb) {
                const float cw = 0.5f * (wa + wb);
                const float vx = x1 - xp, vz = z1 - zp;
                lsum += (vx * vx + vz * vz) * cw;
                csum += cw;
            };
            if (c > 0) term(xv.x, x0, zv.x, z0, w1, w0);
            term(xv.y, xv.x, zv.y, zv.x, w2, w1);
            term(xv.z, xv.y, zv.z, zv.y, w3, w2);
            term(xv.w, xv.z, zv.w, zv.z, w4, w3);
        }
        block_reduce2f(lsum, csum);
        if (threadIdx.x == 0)
            parts[blockIdx.x] = make_double2((double)lsum, (double)csum);
    } else {
        // ---------- recon + vel: 16 consecutive floats per thread -------------
        const int tid = (blockIdx.x - FOOT_BLOCKS) * 256 + threadIdx.x;
        const int c4  = tid * 4;                 // first float4 index
        const int e0  = tid * 16;                // first element index
        const float4* __restrict__ pred4 = reinterpret_cast<const float4*>(pred);
        const float4* __restrict__ targ4 = reinterpret_cast<const float4*>(targ);

        float4 P[4], G[4];
        #pragma unroll
        for (int k = 0; k < 4; ++k) { P[k] = pred4[c4 + k]; G[k] = targ4[c4 + k]; }
        // boundary scalars (L1 hit; only absent at row starts, 1 lane / 2 waves)
        float pm = 0.f, gm = 0.f;
        const int t0 = e0 & (TT - 1);
        if (t0 != 0) { pm = pred[e0 - 1]; gm = targ[e0 - 1]; }

        float d[16];
        #pragma unroll
        for (int k = 0; k < 4; ++k) {
            d[4*k+0] = P[k].x - G[k].x;
            d[4*k+1] = P[k].y - G[k].y;
            d[4*k+2] = P[k].z - G[k].z;
            d[4*k+3] = P[k].w - G[k].w;
        }
        float recon = 0.f, vel = 0.f;
        #pragma unroll
        for (int k = 0; k < 16; ++k) recon += d[k] * d[k];
        #pragma unroll
        for (int k = 1; k < 16; ++k) { const float e = d[k] - d[k-1]; vel += e*e; }
        if (t0 != 0) { const float e = d[0] - (pm - gm); vel += e * e; }

        block_reduce2f(recon, vel);
        if (threadIdx.x == 0)
            parts[blockIdx.x] = make_double2((double)recon, (double)vel);
    }

    // ---------------- last block finalizes --------------------------------
    __shared__ bool amLast;
    if (threadIdx.x == 0) {
        __threadfence();
        amLast = (atomicAdd(counter, 1u) == (unsigned)(NBLK - 1));
    }
    __syncthreads();
    if (!amLast) return;
    __threadfence();

    double fl = 0.0, fc = 0.0, rc = 0.0, vl = 0.0;
    for (int i = threadIdx.x; i < NBLK; i += 256) {
        const double2 v = parts[i];
        if (i < FOOT_BLOCKS) { fl += v.x; fc += v.y; }
        else                 { rc += v.x; vl += v.y; }
    }
    #pragma unroll
    for (int off = 32; off > 0; off >>= 1) {
        rc += __shfl_down(rc, off);
        vl += __shfl_down(vl, off);
        fl += __shfl_down(fl, off);
        fc += __shfl_down(fc, off);
    }
    __shared__ double s4[4][4];
    const int lane = threadIdx.x & 63, wid = threadIdx.x >> 6;
    if (lane == 0) { s4[wid][0]=rc; s4[wid][1]=vl; s4[wid][2]=fl; s4[wid][3]=fc; }
    __syncthreads();
    if (threadIdx.x == 0) {
        for (int w = 1; w < 4; ++w) {
            rc += s4[w][0]; vl += s4[w][1]; fl += s4[w][2]; fc += s4[w][3];
        }
        const double r = rc / (double)NELEM;
        const double v = vl / (double)NVEL;
        const double f = fl / (fc + 1e-8);
        out[0] = (float)(r + 0.2 * v + 0.1 * f);
    }
}

extern "C" void kernel_launch(void* const* d_in, const int* in_sizes, int n_in,
                              void* d_out, int out_size, void* d_ws, size_t ws_size,
                              hipStream_t stream) {
    const float* pred = (const float*)d_in[0];
    const float* targ = (const float*)d_in[1];
    const float* jp   = (const float*)d_in[2];
    float* out        = (float*)d_out;
    unsigned* counter = (unsigned*)d_ws;
    double2* parts    = (double2*)((char*)d_ws + 256);

    hipMemsetAsync(d_ws, 0, 4, stream);   // zero the arrival counter
    fused_kernel<<<NBLK, 256, 0, stream>>>(pred, targ, jp, counter, parts, out);
}

// Round 6
// 190.118 us; speedup vs baseline: 2.1567x; 2.1567x over previous
//
#include <hip/hip_runtime.h>

#define BB 64
#define JJ 24
#define TT 2048
#define NELEM (BB*JJ*6*TT)              // 18,874,368 floats
#define NVEL  ((long long)BB*JJ*6*(TT-1))
#define FOOT_BLOCKS 256
#define RBLOCKS 4608
#define NRT (RBLOCKS*256)               // 1,179,648 recon threads; 4 chunks each
#define NBLK (FOOT_BLOCKS + RBLOCKS)    // 4864 partial slots

__device__ __forceinline__ void block_reduce2f(float& a, float& b) {
    #pragma unroll
    for (int off = 32; off > 0; off >>= 1) {
        a += __shfl_down(a, off);
        b += __shfl_down(b, off);
    }
    __shared__ float sa[4], sb[4];
    const int lane = threadIdx.x & 63;
    const int wid  = threadIdx.x >> 6;
    if (lane == 0) { sa[wid] = a; sb[wid] = b; }
    __syncthreads();
    if (threadIdx.x == 0) {
        for (int w = 1; w < 4; ++w) { a += sa[w]; b += sb[w]; }
    }
}

__device__ __forceinline__ float sigm(float y) {
    return 1.f / (1.f + __expf(-(0.05f - y) * 20.f));
}

__global__ __launch_bounds__(256) void fused_kernel(
        const float* __restrict__ pred, const float* __restrict__ targ,
        const float* __restrict__ jp, double2* __restrict__ parts) {

    if (blockIdx.x < FOOT_BLOCKS) {
        // ---------------- foot-contact loss: one block per (b, foot) ----------
        const int FI[4] = {7, 8, 10, 11};
        const int bf = blockIdx.x;
        const int b  = bf >> 2;
        const int j  = FI[bf & 3];
        const float* __restrict__ xrow = jp + ((size_t)(b * JJ + j) * 3) * TT;
        const float* __restrict__ yrow = xrow + TT;
        const float* __restrict__ zrow = xrow + 2 * TT;
        const float4* __restrict__ x4 = reinterpret_cast<const float4*>(xrow);
        const float4* __restrict__ y4 = reinterpret_cast<const float4*>(yrow);
        const float4* __restrict__ z4 = reinterpret_cast<const float4*>(zrow);

        float lsum = 0.f, csum = 0.f;
        #pragma unroll
        for (int cc = 0; cc < 2; ++cc) {
            const int c = threadIdx.x + cc * 256;         // chunk: t in [4c, 4c+4)
            const float4 xv = x4[c], yv = y4[c], zv = z4[c];
            float x0 = 0.f, y0 = 0.f, z0 = 0.f;
            if (c > 0) { x0 = xrow[4*c-1]; y0 = yrow[4*c-1]; z0 = zrow[4*c-1]; }
            const float w0 = sigm(y0),  w1 = sigm(yv.x), w2 = sigm(yv.y),
                        w3 = sigm(yv.z), w4 = sigm(yv.w);
            auto term = [&](float x1, float xp, float z1, float zp,
                            float wa, float wb) {
                const float cw = 0.5f * (wa + wb);
                const float vx = x1 - xp, vz = z1 - zp;
                lsum += (vx * vx + vz * vz) * cw;
                csum += cw;
            };
            if (c > 0) term(xv.x, x0, zv.x, z0, w1, w0);
            term(xv.y, xv.x, zv.y, zv.x, w2, w1);
            term(xv.z, xv.y, zv.z, zv.y, w3, w2);
            term(xv.w, xv.z, zv.w, zv.z, w4, w3);
        }
        block_reduce2f(lsum, csum);
        if (threadIdx.x == 0)
            parts[blockIdx.x] = make_double2((double)lsum, (double)csum);
    } else {
        // ---- recon + vel: 4 lane-interleaved chunks, all loads independent ---
        const int tid = (blockIdx.x - FOOT_BLOCKS) * 256 + threadIdx.x;
        const float4* __restrict__ pred4 = reinterpret_cast<const float4*>(pred);
        const float4* __restrict__ targ4 = reinterpret_cast<const float4*>(targ);
        // e_k = 4*(tid + k*NRT); 4*NRT % 2048 == 0 -> boundary predicate uniform
        const bool hasb = (tid & 511) != 0;

        float4 P[4], G[4];
        float pm[4], gm[4];
        #pragma unroll
        for (int k = 0; k < 4; ++k) {
            const int c = tid + k * NRT;
            P[k] = pred4[c];
            G[k] = targ4[c];
        }
        #pragma unroll
        for (int k = 0; k < 4; ++k) {
            const int e = 4 * (tid + k * NRT);
            pm[k] = hasb ? pred[e - 1] : 0.f;   // L1 hit: same line lane-1 streams
            gm[k] = hasb ? targ[e - 1] : 0.f;
        }

        float recon = 0.f, vel = 0.f;
        #pragma unroll
        for (int k = 0; k < 4; ++k) {
            const float d0 = P[k].x - G[k].x, d1 = P[k].y - G[k].y,
                        d2 = P[k].z - G[k].z, d3 = P[k].w - G[k].w;
            recon += d0*d0 + d1*d1 + d2*d2 + d3*d3;
            const float e01 = d1 - d0, e12 = d2 - d1, e23 = d3 - d2;
            vel += e01*e01 + e12*e12 + e23*e23;
            if (hasb) { const float b0 = d0 - (pm[k] - gm[k]); vel += b0 * b0; }
        }

        block_reduce2f(recon, vel);
        if (threadIdx.x == 0)
            parts[blockIdx.x] = make_double2((double)recon, (double)vel);
    }
}

// One block reduces all 4864 double2 partials and writes the scalar loss.
__global__ __launch_bounds__(256) void finalize_kernel(
        const double2* __restrict__ parts, float* __restrict__ out) {
    double fl = 0.0, fc = 0.0, rc = 0.0, vl = 0.0;
    for (int i = threadIdx.x; i < NBLK; i += 256) {
        const double2 v = parts[i];
        if (i < FOOT_BLOCKS) { fl += v.x; fc += v.y; }
        else                 { rc += v.x; vl += v.y; }
    }
    #pragma unroll
    for (int off = 32; off > 0; off >>= 1) {
        rc += __shfl_down(rc, off);
        vl += __shfl_down(vl, off);
        fl += __shfl_down(fl, off);
        fc += __shfl_down(fc, off);
    }
    __shared__ double s4[4][4];
    const int lane = threadIdx.x & 63, wid = threadIdx.x >> 6;
    if (lane == 0) { s4[wid][0]=rc; s4[wid][1]=vl; s4[wid][2]=fl; s4[wid][3]=fc; }
    __syncthreads();
    if (threadIdx.x == 0) {
        for (int w = 1; w < 4; ++w) {
            rc += s4[w][0]; vl += s4[w][1]; fl += s4[w][2]; fc += s4[w][3];
        }
        const double r = rc / (double)NELEM;
        const double v = vl / (double)NVEL;
        const double f = fl / (fc + 1e-8);
        out[0] = (float)(r + 0.2 * v + 0.1 * f);
    }
}

extern "C" void kernel_launch(void* const* d_in, const int* in_sizes, int n_in,
                              void* d_out, int out_size, void* d_ws, size_t ws_size,
                              hipStream_t stream) {
    const float* pred = (const float*)d_in[0];
    const float* targ = (const float*)d_in[1];
    const float* jp   = (const float*)d_in[2];
    float* out     = (float*)d_out;
    double2* parts = (double2*)d_ws;

    fused_kernel<<<NBLK, 256, 0, stream>>>(pred, targ, jp, parts);
    finalize_kernel<<<1, 256, 0, stream>>>(parts, out);
}